// Round 6
// baseline (514.462 us; speedup 1.0000x reference)
//
#include <hip/hip_runtime.h>
#include <hip/hip_bf16.h>

// B=4, C=96, vol 32^3; HEADS=4, HDIM=24, FOLD=2, PROP=2.
// 128 cluster batches (B2), each c=24, N=4096 points, M=8 centers.
//
// Key identities:
//   argmax_m chat_m.(f/|f|) = argmax_m (u_m.x + k_m)   [u_m = Wf^T chat_m, f64]
//   sum_n sv*value_n = vW.(sum_n sv*x_n) + (sum_n sv)*vb   [aggregate x, not value]
//
// Pipeline: memset(xagg,cnt) ; k0_prep ; k_pool ; k_cent ; k_prep_u ;
//           k1_conv (argmax+sv) ; k_vagg ; k_sums ; k_disp (dispatch+proj)

// ---------------- K0: weight transposes ------------------------------------
__global__ __launch_bounds__(256) void k0_prep(
    const float* __restrict__ fw, const float* __restrict__ pw,
    float* __restrict__ wfT, float* __restrict__ wpT)
{
    int t = blockIdx.x * 256 + threadIdx.x;
    if (t < 96 * 96) {
        int o = t / 96, c = t % 96;
        wfT[c * 96 + o] = fw[o * 96 + c];
        wpT[c * 96 + o] = pw[o * 96 + c];
    }
}

// ---------------- K_pool: per-octant spatial means of x (f64) ---------------
__global__ __launch_bounds__(256) void k_pool(
    const float* __restrict__ x, double* __restrict__ xmeanD)
{
    int gid = blockIdx.x * 256 + threadIdx.x;      // 24576 total
    int bc = gid >> 6;
    int b = bc / 96, c = bc - b * 96;
    int fm = gid & 63;
    int f1 = (fm >> 5) & 1, f2 = (fm >> 4) & 1, f3 = (fm >> 3) & 1, m = fm & 7;
    int W0 = f1 * 16 + (m >> 2) * 8;
    int H0 = f2 * 16 + ((m >> 1) & 1) * 8;
    int D0 = f3 * 16 + (m & 1) * 8;
    const float* xb = x + ((size_t)b * 96 + c) * 32768;
    double s = 0.0;
    for (int iw = 0; iw < 8; ++iw)
        for (int ih = 0; ih < 8; ++ih) {
            const float4* p = (const float4*)(xb + (W0 + iw) * 1024 + (H0 + ih) * 32 + D0);
            float4 a = p[0], q = p[1];
            s += (double)a.x + (double)a.y + (double)a.z + (double)a.w
               + (double)q.x + (double)q.y + (double)q.z + (double)q.w;
        }
    xmeanD[(size_t)(b * 64 + fm) * 96 + c] = s * (1.0 / 512.0);
}

// ---------------- K_cent: chat (f64) + vcent (f32) --------------------------
__global__ __launch_bounds__(192) void k_cent(
    const float* __restrict__ fw, const float* __restrict__ fb,
    const float* __restrict__ vw, const float* __restrict__ vb,
    const double* __restrict__ xmeanD, double* __restrict__ chat,
    float* __restrict__ vcent)
{
    __shared__ double centL[8][24];
    __shared__ double dnv[8];
    const int B2 = blockIdx.x, t = threadIdx.x;
    const int mm = t / 24, co = t - mm * 24;
    const int b = B2 >> 5, g = (B2 >> 3) & 3, fff = B2 & 7;
    const int ob = g * 24;
    const double* xm = xmeanD + (size_t)(b * 64 + fff * 8 + mm) * 96;
    double cF = (double)fb[ob + co];
    float  cV = vb[ob + co];
    const float* fr = fw + (ob + co) * 96;
    const float* vr = vw + (ob + co) * 96;
    for (int ci = 0; ci < 96; ++ci) {
        double xv = xm[ci];
        cF += (double)fr[ci] * xv;
        cV += vr[ci] * (float)xv;
    }
    centL[mm][co] = cF;
    __syncthreads();
    if (t < 8) {
        double ss = 0.0;
        #pragma unroll
        for (int cc = 0; cc < 24; ++cc) ss += centL[t][cc] * centL[t][cc];
        dnv[t] = fmax(sqrt(ss), 1e-12);
    }
    __syncthreads();
    chat[(size_t)B2 * 192 + mm * 24 + co] = cF / dnv[mm];
    vcent[(size_t)B2 * 192 + t] = cV;
}

// ---------------- K_prep_u: u[B2][m][0..95] = Wf^T chat, [96] = fb.chat -----
__global__ __launch_bounds__(256) void k_prep_u(
    const float* __restrict__ fw, const float* __restrict__ fb,
    const double* __restrict__ chat, double* __restrict__ uG)
{
    int gid = blockIdx.x * 256 + threadIdx.x;
    if (gid >= 128 * 776) return;
    int B2 = gid / 776, rem = gid - B2 * 776;
    int m = rem / 97, c = rem - m * 97;
    int g = (B2 >> 3) & 3;
    const double* ch = chat + (size_t)B2 * 192 + m * 24;
    double s = 0.0;
    if (c < 96) {
        for (int o = 0; o < 24; ++o) s += (double)fw[(g * 24 + o) * 96 + c] * ch[o];
    } else {
        for (int o = 0; o < 24; ++o) s += (double)fb[g * 24 + o] * ch[o];
    }
    uG[gid] = s;
}

// ---------------- K1: fused argmax (f64 u-dots) + sv (f32 norm) -------------
// grid 2048 = b(4) x W(32) x Hq(8) x f3(2); block 256 = 64 pos x 4 heads.
// f3 is block-uniform so u_l reads are pure wave-broadcast.
__global__ __launch_bounds__(256) void k1_conv(
    const float* __restrict__ x, const float* __restrict__ wfT,
    const float* __restrict__ fb, const double* __restrict__ uG,
    const float* __restrict__ al, const float* __restrict__ be,
    float* __restrict__ svb, unsigned char* __restrict__ bmb)
{
    __shared__ float xt[96][64];
    __shared__ double u_l[4][776];
    const int tile = blockIdx.x;
    const int b = tile >> 9;
    const int r = tile & 511;
    const int W = r >> 4;
    const int Hq = (r >> 1) & 7;
    const int f3 = r & 1;
    const int f1 = W >> 4, f2 = Hq >> 2;
    const float* xb = x + (size_t)b * 96 * 32768 + W * 1024 + Hq * 4 * 32 + f3 * 16;

    #pragma unroll
    for (int k = 0; k < 24; ++k) {
        int idx = k * 256 + threadIdx.x;
        int c = idx >> 6, i2 = idx & 63;
        xt[c][i2] = xb[(size_t)c * 32768 + (i2 >> 4) * 32 + (i2 & 15)];
    }
    #pragma unroll
    for (int g = 0; g < 4; ++g) {
        int B2g = (b << 5) | (g << 3) | (f1 << 2) | (f2 << 1) | f3;
        for (int k = threadIdx.x; k < 776; k += 256)
            u_l[g][k] = uG[(size_t)B2g * 776 + k];
    }
    __syncthreads();

    const int i = threadIdx.x & 63;
    const int g = threadIdx.x >> 6;
    const int ob = __builtin_amdgcn_readfirstlane(g * 24);
    const double* ug = u_l[g];           // wave-uniform LDS base -> broadcast

    double a[8];
    #pragma unroll
    for (int m = 0; m < 8; ++m) a[m] = ug[m * 97 + 96];
    float accN[24];
    #pragma unroll
    for (int oo = 0; oo < 24; ++oo) accN[oo] = fb[ob + oo];

    for (int c = 0; c < 96; ++c) {
        const float xv = xt[c][i];
        const double xd = (double)xv;
        #pragma unroll
        for (int m = 0; m < 8; ++m) a[m] = fma(xd, ug[m * 97 + c], a[m]);
        const float* wr = wfT + c * 96 + ob;     // wave-uniform -> s_load
        #pragma unroll
        for (int oo = 0; oo < 24; ++oo) accN[oo] = fmaf(xv, wr[oo], accN[oo]);
    }

    float ss = 0.f;
    #pragma unroll
    for (int oo = 0; oo < 24; ++oo) ss = fmaf(accN[oo], accN[oo], ss);
    const float dn = fmaxf(sqrtf(ss), 1e-12f);

    const double alpha = (double)al[0];
    const double beta  = (double)be[0];
    int bm = 0; double dbest = a[0];
    if (alpha > 0.0) {
        #pragma unroll
        for (int m = 1; m < 8; ++m) if (a[m] > dbest) { dbest = a[m]; bm = m; }
    } else if (alpha < 0.0) {
        #pragma unroll
        for (int m = 1; m < 8; ++m) if (a[m] < dbest) { dbest = a[m]; bm = m; }
    }
    const double tv = beta + alpha * (dbest / (double)dn);
    const float sv = 1.f / (1.f + expf(-(float)tv));

    const int n = ((W & 15) << 8) | (((Hq & 3) * 4 + (i >> 4)) << 4) | (i & 15);
    const int B2 = (b << 5) | (g << 3) | (f1 << 2) | (f2 << 1) | f3;
    svb[(size_t)B2 * 4096 + n] = sv;
    bmb[(size_t)B2 * 4096 + n] = (unsigned char)bm;
}

// ---------------- K_vagg: sv-weighted x aggregation -------------------------
// grid 256 = (b,fff)(32) x chunk(8); block 256 (4 waves x 64 pts).
__global__ __launch_bounds__(256) void k_vagg(
    const float* __restrict__ x, const float* __restrict__ svb,
    const unsigned char* __restrict__ bmb, float* __restrict__ xagg,
    float* __restrict__ cntb)
{
    __shared__ float svs[4][512];
    __shared__ unsigned char bms[4][512];
    __shared__ float bins[4][8][96];
    __shared__ float binc[4][8];
    const int bid = blockIdx.x;
    const int chunk = bid & 7;
    const int bf = bid >> 3;
    const int b = bf >> 3, fff = bf & 7;
    const int f1 = fff >> 2, f2 = (fff >> 1) & 1, f3 = fff & 1;
    const int t = threadIdx.x;

    for (int k = t; k < 4 * 8 * 96; k += 256) ((float*)bins)[k] = 0.f;
    if (t < 32) ((float*)binc)[t] = 0.f;
    #pragma unroll
    for (int g = 0; g < 4; ++g) {
        int B2g = (b << 5) | (g << 3) | fff;
        #pragma unroll
        for (int rr = 0; rr < 2; ++rr) {
            int q = rr * 256 + t;
            svs[g][q] = svb[(size_t)B2g * 4096 + chunk * 512 + q];
            bms[g][q] = bmb[(size_t)B2g * 4096 + chunk * 512 + q];
        }
    }
    __syncthreads();

    const int w = t >> 6, lane = t & 63;
    const float* xbase = x + (size_t)b * 96 * 32768;
    #pragma unroll
    for (int pb = 0; pb < 2; ++pb) {
        const int q = w * 128 + pb * 64 + lane;
        const int n = chunk * 512 + q;
        const int s = (f1 * 16 + (n >> 8)) * 1024 + (f2 * 16 + ((n >> 4) & 15)) * 32
                    + f3 * 16 + (n & 15);
        const float sv0 = svs[0][q], sv1 = svs[1][q], sv2 = svs[2][q], sv3 = svs[3][q];
        const int m0 = bms[0][q], m1 = bms[1][q], m2 = bms[2][q], m3 = bms[3][q];
        atomicAdd(&binc[0][m0], sv0); atomicAdd(&binc[1][m1], sv1);
        atomicAdd(&binc[2][m2], sv2); atomicAdd(&binc[3][m3], sv3);
        for (int c = 0; c < 96; ++c) {
            const float xv = xbase[(size_t)c * 32768 + s];
            atomicAdd(&bins[0][m0][c], sv0 * xv);
            atomicAdd(&bins[1][m1][c], sv1 * xv);
            atomicAdd(&bins[2][m2][c], sv2 * xv);
            atomicAdd(&bins[3][m3][c], sv3 * xv);
        }
    }
    __syncthreads();
    for (int k = t; k < 4 * 8 * 96; k += 256) {
        int g = k / 768, rem = k - g * 768;
        int m = rem / 96, c = rem - m * 96;
        int B2g = (b << 5) | (g << 3) | fff;
        atomicAdd(&xagg[((size_t)B2g * 8 + m) * 96 + c], ((float*)bins)[k]);
    }
    if (t < 32) {
        int g = t >> 3, m = t & 7;
        int B2g = (b << 5) | (g << 3) | fff;
        atomicAdd(&cntb[B2g * 8 + m], binc[g][m]);
    }
}

// ---------------- K_sums: sums = vW . xagg + cnt*vb -------------------------
__global__ __launch_bounds__(192) void k_sums(
    const float* __restrict__ vw, const float* __restrict__ vb,
    const float* __restrict__ xagg, const float* __restrict__ cntb,
    float* __restrict__ sums)
{
    const int B2 = blockIdx.x, t = threadIdx.x;
    const int m = t / 24, co = t - m * 24;
    const int g = (B2 >> 3) & 3;
    const float* xa = xagg + ((size_t)B2 * 8 + m) * 96;
    const float* vr = vw + (g * 24 + co) * 96;
    float s = 0.f;
    for (int ci = 0; ci < 96; ++ci) s = fmaf(vr[ci], xa[ci], s);
    sums[(size_t)B2 * 192 + t] = s + cntb[B2 * 8 + m] * vb[g * 24 + co];
}

// ---------------- K_disp: agg finalize + dispatch + unfold + projection -----
__global__ __launch_bounds__(256) void k_disp(
    const float* __restrict__ sums, const float* __restrict__ cnt,
    const float* __restrict__ vcent, const float* __restrict__ svb,
    const unsigned char* __restrict__ bmb, const float* __restrict__ wpT,
    const float* __restrict__ pb, float* __restrict__ out)
{
    __shared__ float xt[96][64];
    __shared__ float agg_l[8][8][24];     // [slot][m][c]
    const int tile = blockIdx.x;
    const int b = tile >> 9;
    const int s0 = (tile & 511) << 6;
    const int f1 = (s0 >> 14) & 1, f2 = (s0 >> 9) & 1;
    for (int k = threadIdx.x; k < 1536; k += 256) {
        int slot = k / 192, rem = k - slot * 192;
        int g = slot >> 1, f3 = slot & 1;
        int B2 = (b << 5) | (g << 3) | (f1 << 2) | (f2 << 1) | f3;
        int mm = rem / 24;
        ((float*)agg_l)[k] =
            (sums[(size_t)B2 * 192 + rem] + vcent[(size_t)B2 * 192 + rem]) /
            (cnt[B2 * 8 + mm] + 1.f);
    }
    __syncthreads();

    const int i = threadIdx.x & 63;
    const int g = threadIdx.x >> 6;
    const int s = s0 + i;
    const int D = s & 31, H = (s >> 5) & 31, W = s >> 10;
    const int f3 = D >> 4;
    const int n = ((W & 15) << 8) | ((H & 15) << 4) | (D & 15);
    const int B2 = (b << 5) | (g << 3) | (f1 << 2) | (f2 << 1) | f3;
    const int slot = (g << 1) | f3;
    const float svv = svb[(size_t)B2 * 4096 + n];
    const int bmv = bmb[(size_t)B2 * 4096 + n];
    #pragma unroll
    for (int c = 0; c < 24; ++c) xt[g * 24 + c][i] = svv * agg_l[slot][bmv][c];
    __syncthreads();

    const int ob = __builtin_amdgcn_readfirstlane(g * 24);
    float acc[24];
    #pragma unroll
    for (int oo = 0; oo < 24; ++oo) acc[oo] = pb[ob + oo];
    for (int c = 0; c < 96; ++c) {
        float xv = xt[c][i];
        const float* wr = wpT + c * 96 + ob;
        #pragma unroll
        for (int oo = 0; oo < 24; ++oo) acc[oo] = fmaf(wr[oo], xv, acc[oo]);
    }
    #pragma unroll
    for (int oo = 0; oo < 24; ++oo)
        out[((size_t)b * 96 + ob + oo) * 32768 + s0 + i] = acc[oo];
}

// ---------------- launcher --------------------------------------------------
extern "C" void kernel_launch(void* const* d_in, const int* in_sizes, int n_in,
                              void* d_out, int out_size, void* d_ws, size_t ws_size,
                              hipStream_t stream)
{
    const float* x  = (const float*)d_in[0];
    const float* fw = (const float*)d_in[1];
    const float* fb = (const float*)d_in[2];
    const float* vw = (const float*)d_in[3];
    const float* vb = (const float*)d_in[4];
    const float* pw = (const float*)d_in[5];
    const float* pb = (const float*)d_in[6];
    const float* al = (const float*)d_in[7];
    const float* be = (const float*)d_in[8];
    float* out = (float*)d_out;

    char* ws = (char*)d_ws;
    float*  wfT   = (float*)(ws);                    //   36864 B
    float*  wpT   = (float*)(ws + 36864);            //   36864 B
    double* xmeanD= (double*)(ws + 73728);           //  196608 B
    double* chat  = (double*)(ws + 270336);          //  196608 B
    double* uG    = (double*)(ws + 466944);          //  794624 B [128][8][97]
    float*  vcent = (float*)(ws + 1261568);          //   98304 B
    float*  sums  = (float*)(ws + 1359872);          //   98304 B
    float*  xagg  = (float*)(ws + 1458176);          //  393216 B
    float*  cntb  = (float*)(ws + 1851392);          //    4096 B
    float*  svb   = (float*)(ws + 1855488);          // 2097152 B
    unsigned char* bmb = (unsigned char*)(ws + 3952640); // 524288 B
    // total ~4.5 MB

    hipMemsetAsync(xagg, 0, 393216 + 4096, stream);  // xagg + cntb contiguous
    k0_prep<<<36, 256, 0, stream>>>(fw, pw, wfT, wpT);
    k_pool<<<96, 256, 0, stream>>>(x, xmeanD);
    k_cent<<<128, 192, 0, stream>>>(fw, fb, vw, vb, xmeanD, chat, vcent);
    k_prep_u<<<388, 256, 0, stream>>>(fw, fb, chat, uG);
    k1_conv<<<2048, 256, 0, stream>>>(x, wfT, fb, uG, al, be, svb, bmb);
    k_vagg<<<256, 256, 0, stream>>>(x, svb, bmb, xagg, cntb);
    k_sums<<<128, 192, 0, stream>>>(vw, vb, xagg, cntb, sums);
    k_disp<<<2048, 256, 0, stream>>>(sums, cntb, vcent, svb, bmb, wpT, pb, out);
}

// Round 7
// 283.572 us; speedup vs baseline: 1.8142x; 1.8142x over previous
//
#include <hip/hip_runtime.h>
#include <hip/hip_bf16.h>

// B=4, C=96, vol 32^3; HEADS=4, HDIM=24, FOLD=2, PROP=2.
// 128 cluster batches (B2), each c=24, N=4096 points, M=8 centers.
//
// Key identities:
//   argmax_m chat_m.(f/|f|) = argmax_m (u_m.x + k_m)   [u_m = Wf^T chat_m, f64]
//   sum_n sv*value_n = vW.(sum_n sv*x_n) + (sum_n sv)*vb   [aggregate x, not value]
//   masked aggregation = dense mask-GEMM (branchless cndmask, NO atomics)
//
// Pipeline: k0_prep ; k_pool ; k_cent ; k_prep_u ; k1_conv ; k_xagg ; k_sums ; k_disp

// ---------------- K0: weight transposes ------------------------------------
__global__ __launch_bounds__(256) void k0_prep(
    const float* __restrict__ fw, const float* __restrict__ pw,
    float* __restrict__ wfT, float* __restrict__ wpT)
{
    int t = blockIdx.x * 256 + threadIdx.x;
    if (t < 96 * 96) {
        int o = t / 96, c = t % 96;
        wfT[c * 96 + o] = fw[o * 96 + c];
        wpT[c * 96 + o] = pw[o * 96 + c];
    }
}

// ---------------- K_pool: per-octant spatial means of x (f64) ---------------
__global__ __launch_bounds__(256) void k_pool(
    const float* __restrict__ x, double* __restrict__ xmeanD)
{
    int gid = blockIdx.x * 256 + threadIdx.x;      // 24576 total
    int bc = gid >> 6;
    int b = bc / 96, c = bc - b * 96;
    int fm = gid & 63;
    int f1 = (fm >> 5) & 1, f2 = (fm >> 4) & 1, f3 = (fm >> 3) & 1, m = fm & 7;
    int W0 = f1 * 16 + (m >> 2) * 8;
    int H0 = f2 * 16 + ((m >> 1) & 1) * 8;
    int D0 = f3 * 16 + (m & 1) * 8;
    const float* xb = x + ((size_t)b * 96 + c) * 32768;
    double s = 0.0;
    for (int iw = 0; iw < 8; ++iw)
        for (int ih = 0; ih < 8; ++ih) {
            const float4* p = (const float4*)(xb + (W0 + iw) * 1024 + (H0 + ih) * 32 + D0);
            float4 a = p[0], q = p[1];
            s += (double)a.x + (double)a.y + (double)a.z + (double)a.w
               + (double)q.x + (double)q.y + (double)q.z + (double)q.w;
        }
    xmeanD[(size_t)(b * 64 + fm) * 96 + c] = s * (1.0 / 512.0);
}

// ---------------- K_cent: chat (f64) + vcent (f32) --------------------------
__global__ __launch_bounds__(192) void k_cent(
    const float* __restrict__ fw, const float* __restrict__ fb,
    const float* __restrict__ vw, const float* __restrict__ vb,
    const double* __restrict__ xmeanD, double* __restrict__ chat,
    float* __restrict__ vcent)
{
    __shared__ double centL[8][24];
    __shared__ double dnv[8];
    const int B2 = blockIdx.x, t = threadIdx.x;
    const int mm = t / 24, co = t - mm * 24;
    const int b = B2 >> 5, g = (B2 >> 3) & 3, fff = B2 & 7;
    const int ob = g * 24;
    const double* xm = xmeanD + (size_t)(b * 64 + fff * 8 + mm) * 96;
    double cF = (double)fb[ob + co];
    float  cV = vb[ob + co];
    const float* fr = fw + (ob + co) * 96;
    const float* vr = vw + (ob + co) * 96;
    for (int ci = 0; ci < 96; ++ci) {
        double xv = xm[ci];
        cF += (double)fr[ci] * xv;
        cV += vr[ci] * (float)xv;
    }
    centL[mm][co] = cF;
    __syncthreads();
    if (t < 8) {
        double ss = 0.0;
        #pragma unroll
        for (int cc = 0; cc < 24; ++cc) ss += centL[t][cc] * centL[t][cc];
        dnv[t] = fmax(sqrt(ss), 1e-12);
    }
    __syncthreads();
    chat[(size_t)B2 * 192 + mm * 24 + co] = cF / dnv[mm];
    vcent[(size_t)B2 * 192 + t] = cV;
}

// ---------------- K_prep_u: u[B2][m][0..95] = Wf^T chat, [96] = fb.chat -----
__global__ __launch_bounds__(256) void k_prep_u(
    const float* __restrict__ fw, const float* __restrict__ fb,
    const double* __restrict__ chat, double* __restrict__ uG)
{
    int gid = blockIdx.x * 256 + threadIdx.x;
    if (gid >= 128 * 776) return;
    int B2 = gid / 776, rem = gid - B2 * 776;
    int m = rem / 97, c = rem - m * 97;
    int g = (B2 >> 3) & 3;
    const double* ch = chat + (size_t)B2 * 192 + m * 24;
    double s = 0.0;
    if (c < 96) {
        for (int o = 0; o < 24; ++o) s += (double)fw[(g * 24 + o) * 96 + c] * ch[o];
    } else {
        for (int o = 0; o < 24; ++o) s += (double)fb[g * 24 + o] * ch[o];
    }
    uG[gid] = s;
}

// ---------------- K1: fused argmax (f64 u-dots) + sv (f32 norm) -------------
// grid 2048 = b(4) x W(32) x Hq(8) x f3(2); block 256 = 64 pos x 4 heads.
__global__ __launch_bounds__(256) void k1_conv(
    const float* __restrict__ x, const float* __restrict__ wfT,
    const float* __restrict__ fb, const double* __restrict__ uG,
    const float* __restrict__ al, const float* __restrict__ be,
    float* __restrict__ svb, unsigned char* __restrict__ bmb)
{
    __shared__ float xt[96][64];
    __shared__ double u_l[4][776];
    const int tile = blockIdx.x;
    const int b = tile >> 9;
    const int r = tile & 511;
    const int W = r >> 4;
    const int Hq = (r >> 1) & 7;
    const int f3 = r & 1;
    const int f1 = W >> 4, f2 = Hq >> 2;
    const float* xb = x + (size_t)b * 96 * 32768 + W * 1024 + Hq * 4 * 32 + f3 * 16;

    #pragma unroll
    for (int k = 0; k < 24; ++k) {
        int idx = k * 256 + threadIdx.x;
        int c = idx >> 6, i2 = idx & 63;
        xt[c][i2] = xb[(size_t)c * 32768 + (i2 >> 4) * 32 + (i2 & 15)];
    }
    #pragma unroll
    for (int g = 0; g < 4; ++g) {
        int B2g = (b << 5) | (g << 3) | (f1 << 2) | (f2 << 1) | f3;
        for (int k = threadIdx.x; k < 776; k += 256)
            u_l[g][k] = uG[(size_t)B2g * 776 + k];
    }
    __syncthreads();

    const int i = threadIdx.x & 63;
    const int g = threadIdx.x >> 6;
    const int ob = __builtin_amdgcn_readfirstlane(g * 24);
    const double* ug = u_l[g];           // wave-uniform LDS base -> broadcast

    double a[8];
    #pragma unroll
    for (int m = 0; m < 8; ++m) a[m] = ug[m * 97 + 96];
    float accN[24];
    #pragma unroll
    for (int oo = 0; oo < 24; ++oo) accN[oo] = fb[ob + oo];

    for (int c = 0; c < 96; ++c) {
        const float xv = xt[c][i];
        const double xd = (double)xv;
        #pragma unroll
        for (int m = 0; m < 8; ++m) a[m] = fma(xd, ug[m * 97 + c], a[m]);
        const float* wr = wfT + c * 96 + ob;     // wave-uniform -> s_load
        #pragma unroll
        for (int oo = 0; oo < 24; ++oo) accN[oo] = fmaf(xv, wr[oo], accN[oo]);
    }

    float ss = 0.f;
    #pragma unroll
    for (int oo = 0; oo < 24; ++oo) ss = fmaf(accN[oo], accN[oo], ss);
    const float dn = fmaxf(sqrtf(ss), 1e-12f);

    const double alpha = (double)al[0];
    const double beta  = (double)be[0];
    int bm = 0; double dbest = a[0];
    if (alpha > 0.0) {
        #pragma unroll
        for (int m = 1; m < 8; ++m) if (a[m] > dbest) { dbest = a[m]; bm = m; }
    } else if (alpha < 0.0) {
        #pragma unroll
        for (int m = 1; m < 8; ++m) if (a[m] < dbest) { dbest = a[m]; bm = m; }
    }
    const double tv = beta + alpha * (dbest / (double)dn);
    const float sv = 1.f / (1.f + expf(-(float)tv));

    const int n = ((W & 15) << 8) | (((Hq & 3) * 4 + (i >> 4)) << 4) | (i & 15);
    const int B2 = (b << 5) | (g << 3) | (f1 << 2) | (f2 << 1) | f3;
    svb[(size_t)B2 * 4096 + n] = sv;
    bmb[(size_t)B2 * 4096 + n] = (unsigned char)bm;
}

// ---------------- K_xagg: branchless mask-GEMM aggregation (no atomics) -----
// grid 3104 = 32 groups (b,fff) x 97 c-slots (c==96 -> cnt with xv=1).
// block 256; thread holds 32 static accumulators (4g x 8m); LDS tree reduce.
__global__ __launch_bounds__(256) void k_xagg(
    const float* __restrict__ x, const float* __restrict__ svb,
    const unsigned char* __restrict__ bmb, float* __restrict__ xagg,
    float* __restrict__ cntb)
{
    __shared__ float red[256][33];   // padded: conflict-free dump
    __shared__ float red2[8][32];
    const int grp = blockIdx.x / 97;
    const int c   = blockIdx.x - grp * 97;
    const int b = grp >> 3, fff = grp & 7;
    const int f1 = fff >> 2, f2 = (fff >> 1) & 1, f3 = fff & 1;
    const int t = threadIdx.x;
    const float* xc = x + ((size_t)b * 96 + (c < 96 ? c : 0)) * 32768;
    const int sbase = f1 * 16 * 1024 + f2 * 16 * 32 + f3 * 16;

    float acc[4][8];
    #pragma unroll
    for (int g = 0; g < 4; ++g)
        #pragma unroll
        for (int m = 0; m < 8; ++m) acc[g][m] = 0.f;

    #pragma unroll 4
    for (int k = 0; k < 16; ++k) {
        const int n = k * 256 + t;
        const int s = sbase + (n >> 8) * 1024 + ((n >> 4) & 15) * 32 + (n & 15);
        const float xv = (c < 96) ? xc[s] : 1.0f;
        #pragma unroll
        for (int g = 0; g < 4; ++g) {
            const int B2g = (b << 5) | (g << 3) | fff;
            const float svv = svb[(size_t)B2g * 4096 + n];
            const int bmv = bmb[(size_t)B2g * 4096 + n];
            const float p = svv * xv;
            #pragma unroll
            for (int m = 0; m < 8; ++m)
                acc[g][m] += (bmv == m) ? p : 0.f;
        }
    }

    // dump to LDS (static j indexing) and tree-reduce over threads
    #pragma unroll
    for (int g = 0; g < 4; ++g)
        #pragma unroll
        for (int m = 0; m < 8; ++m) red[t][g * 8 + m] = acc[g][m];
    __syncthreads();
    {
        const int j = t & 31, part = t >> 5;   // 8 parts x 32 outputs
        float s = 0.f;
        #pragma unroll
        for (int kk = 0; kk < 32; ++kk) s += red[part * 32 + kk][j];
        red2[part][j] = s;
    }
    __syncthreads();
    if (t < 32) {
        float s = 0.f;
        #pragma unroll
        for (int p = 0; p < 8; ++p) s += red2[p][t];
        const int g = t >> 3, m = t & 7;
        const int B2g = (b << 5) | (g << 3) | fff;
        if (c < 96) xagg[((size_t)B2g * 8 + m) * 96 + c] = s;
        else        cntb[B2g * 8 + m] = s;
    }
}

// ---------------- K_sums: sums = vW . xagg + cnt*vb -------------------------
__global__ __launch_bounds__(192) void k_sums(
    const float* __restrict__ vw, const float* __restrict__ vb,
    const float* __restrict__ xagg, const float* __restrict__ cntb,
    float* __restrict__ sums)
{
    const int B2 = blockIdx.x, t = threadIdx.x;
    const int m = t / 24, co = t - m * 24;
    const int g = (B2 >> 3) & 3;
    const float* xa = xagg + ((size_t)B2 * 8 + m) * 96;
    const float* vr = vw + (g * 24 + co) * 96;
    float s = 0.f;
    for (int ci = 0; ci < 96; ++ci) s = fmaf(vr[ci], xa[ci], s);
    sums[(size_t)B2 * 192 + t] = s + cntb[B2 * 8 + m] * vb[g * 24 + co];
}

// ---------------- K_disp: agg finalize + dispatch + unfold + projection -----
__global__ __launch_bounds__(256) void k_disp(
    const float* __restrict__ sums, const float* __restrict__ cnt,
    const float* __restrict__ vcent, const float* __restrict__ svb,
    const unsigned char* __restrict__ bmb, const float* __restrict__ wpT,
    const float* __restrict__ pb, float* __restrict__ out)
{
    __shared__ float xt[96][64];
    __shared__ float agg_l[8][8][24];     // [slot][m][c]
    const int tile = blockIdx.x;
    const int b = tile >> 9;
    const int s0 = (tile & 511) << 6;
    const int f1 = (s0 >> 14) & 1, f2 = (s0 >> 9) & 1;
    for (int k = threadIdx.x; k < 1536; k += 256) {
        int slot = k / 192, rem = k - slot * 192;
        int g = slot >> 1, f3 = slot & 1;
        int B2 = (b << 5) | (g << 3) | (f1 << 2) | (f2 << 1) | f3;
        int mm = rem / 24;
        ((float*)agg_l)[k] =
            (sums[(size_t)B2 * 192 + rem] + vcent[(size_t)B2 * 192 + rem]) /
            (cnt[B2 * 8 + mm] + 1.f);
    }
    __syncthreads();

    const int i = threadIdx.x & 63;
    const int g = threadIdx.x >> 6;
    const int s = s0 + i;
    const int D = s & 31, H = (s >> 5) & 31, W = s >> 10;
    const int f3 = D >> 4;
    const int n = ((W & 15) << 8) | ((H & 15) << 4) | (D & 15);
    const int B2 = (b << 5) | (g << 3) | (f1 << 2) | (f2 << 1) | f3;
    const int slot = (g << 1) | f3;
    const float svv = svb[(size_t)B2 * 4096 + n];
    const int bmv = bmb[(size_t)B2 * 4096 + n];
    #pragma unroll
    for (int c = 0; c < 24; ++c) xt[g * 24 + c][i] = svv * agg_l[slot][bmv][c];
    __syncthreads();

    const int ob = __builtin_amdgcn_readfirstlane(g * 24);
    float acc[24];
    #pragma unroll
    for (int oo = 0; oo < 24; ++oo) acc[oo] = pb[ob + oo];
    for (int c = 0; c < 96; ++c) {
        float xv = xt[c][i];
        const float* wr = wpT + c * 96 + ob;
        #pragma unroll
        for (int oo = 0; oo < 24; ++oo) acc[oo] = fmaf(wr[oo], xv, acc[oo]);
    }
    #pragma unroll
    for (int oo = 0; oo < 24; ++oo)
        out[((size_t)b * 96 + ob + oo) * 32768 + s0 + i] = acc[oo];
}

// ---------------- launcher --------------------------------------------------
extern "C" void kernel_launch(void* const* d_in, const int* in_sizes, int n_in,
                              void* d_out, int out_size, void* d_ws, size_t ws_size,
                              hipStream_t stream)
{
    const float* x  = (const float*)d_in[0];
    const float* fw = (const float*)d_in[1];
    const float* fb = (const float*)d_in[2];
    const float* vw = (const float*)d_in[3];
    const float* vb = (const float*)d_in[4];
    const float* pw = (const float*)d_in[5];
    const float* pb = (const float*)d_in[6];
    const float* al = (const float*)d_in[7];
    const float* be = (const float*)d_in[8];
    float* out = (float*)d_out;

    char* ws = (char*)d_ws;
    float*  wfT   = (float*)(ws);                    //   36864 B
    float*  wpT   = (float*)(ws + 36864);            //   36864 B
    double* xmeanD= (double*)(ws + 73728);           //  196608 B
    double* chat  = (double*)(ws + 270336);          //  196608 B
    double* uG    = (double*)(ws + 466944);          //  794624 B [128][8][97]
    float*  vcent = (float*)(ws + 1261568);          //   98304 B
    float*  sums  = (float*)(ws + 1359872);          //   98304 B
    float*  xagg  = (float*)(ws + 1458176);          //  393216 B
    float*  cntb  = (float*)(ws + 1851392);          //    4096 B
    float*  svb   = (float*)(ws + 1855488);          // 2097152 B
    unsigned char* bmb = (unsigned char*)(ws + 3952640); // 524288 B
    // total ~4.5 MB

    k0_prep<<<36, 256, 0, stream>>>(fw, pw, wfT, wpT);
    k_pool<<<96, 256, 0, stream>>>(x, xmeanD);
    k_cent<<<128, 192, 0, stream>>>(fw, fb, vw, vb, xmeanD, chat, vcent);
    k_prep_u<<<388, 256, 0, stream>>>(fw, fb, chat, uG);
    k1_conv<<<2048, 256, 0, stream>>>(x, wfT, fb, uG, al, be, svb, bmb);
    k_xagg<<<3104, 256, 0, stream>>>(x, svb, bmb, xagg, cntb);
    k_sums<<<128, 192, 0, stream>>>(vw, vb, xagg, cntb, sums);
    k_disp<<<2048, 256, 0, stream>>>(sums, cntb, vcent, svb, bmb, wpT, pb, out);
}

// Round 8
// 248.792 us; speedup vs baseline: 2.0678x; 1.1398x over previous
//
#include <hip/hip_runtime.h>
#include <hip/hip_bf16.h>

// B=4, C=96, vol 32^3; HEADS=4, HDIM=24, FOLD=2, PROP=2.
// 128 cluster batches (B2), each c=24, N=4096 points, M=8 centers.
//
// Identities:
//   argmax_m chat_m.(f/|f|) = argmax_m (u_m.x + k_m)    [u = Wf^T chat, f64]
//   sum_n sv*value_n = vW.(sum_n sv*x_n) + (sum_n sv)*vb [aggregate x]
//   out = pb + sum_g sv_g * pagg[B2g][bm_g]              [pagg = P.agg]
//
// Pipeline: k0_prep ; k_pool ; k_cent ; k_prep_u ; k1_conv ; k_xagg ;
//           k_pagg ; k_disp

// ---------------- K0: weight transposes ------------------------------------
__global__ __launch_bounds__(256) void k0_prep(
    const float* __restrict__ fw, const float* __restrict__ vw,
    const float* __restrict__ pw, float* __restrict__ wfT,
    float* __restrict__ wvT, float* __restrict__ wpT)
{
    int t = blockIdx.x * 256 + threadIdx.x;
    if (t < 96 * 96) {
        int o = t / 96, c = t % 96;
        wfT[c * 96 + o] = fw[o * 96 + c];
        wvT[c * 96 + o] = vw[o * 96 + c];
        wpT[c * 96 + o] = pw[o * 96 + c];
    }
}

// ---------------- K_pool: per-octant spatial means of x (f64) ---------------
__global__ __launch_bounds__(256) void k_pool(
    const float* __restrict__ x, double* __restrict__ xmeanD)
{
    int gid = blockIdx.x * 256 + threadIdx.x;      // 24576 total
    int bc = gid >> 6;
    int b = bc / 96, c = bc - b * 96;
    int fm = gid & 63;
    int f1 = (fm >> 5) & 1, f2 = (fm >> 4) & 1, f3 = (fm >> 3) & 1, m = fm & 7;
    int W0 = f1 * 16 + (m >> 2) * 8;
    int H0 = f2 * 16 + ((m >> 1) & 1) * 8;
    int D0 = f3 * 16 + (m & 1) * 8;
    const float* xb = x + ((size_t)b * 96 + c) * 32768;
    double s = 0.0;
    for (int iw = 0; iw < 8; ++iw)
        for (int ih = 0; ih < 8; ++ih) {
            const float4* p = (const float4*)(xb + (W0 + iw) * 1024 + (H0 + ih) * 32 + D0);
            float4 a = p[0], q = p[1];
            s += (double)a.x + (double)a.y + (double)a.z + (double)a.w
               + (double)q.x + (double)q.y + (double)q.z + (double)q.w;
        }
    xmeanD[(size_t)(b * 64 + fm) * 96 + c] = s * (1.0 / 512.0);
}

// ---------------- K_cent: chat (f64) + vcent (f32) --------------------------
__global__ __launch_bounds__(192) void k_cent(
    const float* __restrict__ fw, const float* __restrict__ fb,
    const float* __restrict__ vw, const float* __restrict__ vb,
    const double* __restrict__ xmeanD, double* __restrict__ chat,
    float* __restrict__ vcent)
{
    __shared__ double centL[8][24];
    __shared__ double dnv[8];
    const int B2 = blockIdx.x, t = threadIdx.x;
    const int mm = t / 24, co = t - mm * 24;
    const int b = B2 >> 5, g = (B2 >> 3) & 3, fff = B2 & 7;
    const int ob = g * 24;
    const double* xm = xmeanD + (size_t)(b * 64 + fff * 8 + mm) * 96;
    double cF = (double)fb[ob + co];
    float  cV = vb[ob + co];
    const float* fr = fw + (ob + co) * 96;
    const float* vr = vw + (ob + co) * 96;
    for (int ci = 0; ci < 96; ++ci) {
        double xv = xm[ci];
        cF += (double)fr[ci] * xv;
        cV += vr[ci] * (float)xv;
    }
    centL[mm][co] = cF;
    __syncthreads();
    if (t < 8) {
        double ss = 0.0;
        #pragma unroll
        for (int cc = 0; cc < 24; ++cc) ss += centL[t][cc] * centL[t][cc];
        dnv[t] = fmax(sqrt(ss), 1e-12);
    }
    __syncthreads();
    chat[(size_t)B2 * 192 + mm * 24 + co] = cF / dnv[mm];
    vcent[(size_t)B2 * 192 + t] = cV;
}

// ---------------- K_prep_u: uG[B2][c][m] (c==96 -> bias row) ----------------
__global__ __launch_bounds__(256) void k_prep_u(
    const float* __restrict__ fw, const float* __restrict__ fb,
    const double* __restrict__ chat, double* __restrict__ uG)
{
    int gid = blockIdx.x * 256 + threadIdx.x;
    if (gid >= 128 * 776) return;
    int B2 = gid / 776, rem = gid - B2 * 776;
    int c = rem >> 3, m = rem & 7;
    int g = (B2 >> 3) & 3;
    const double* ch = chat + (size_t)B2 * 192 + m * 24;
    double s = 0.0;
    if (c < 96) {
        for (int o = 0; o < 24; ++o) s += (double)fw[(g * 24 + o) * 96 + c] * ch[o];
    } else {
        for (int o = 0; o < 24; ++o) s += (double)fb[g * 24 + o] * ch[o];
    }
    uG[(size_t)B2 * 776 + c * 8 + m] = s;
}

// ---------------- K1: fused argmax (f64 u-dots via s_load) + sv -------------
// grid 2048 = b(4) x W(32) x Hq(8) x f3(2); block 256 = 64 pos x 4 heads.
// u reads are wave-uniform -> scalar loads (no LDS staging of u).
__global__ __launch_bounds__(256) void k1_conv(
    const float* __restrict__ x, const float* __restrict__ wfT,
    const float* __restrict__ fb, const double* __restrict__ uG,
    const float* __restrict__ al, const float* __restrict__ be,
    float* __restrict__ svb, unsigned char* __restrict__ bmb)
{
    __shared__ float xt[96][64];
    const int tile = blockIdx.x;
    const int b = tile >> 9;
    const int r = tile & 511;
    const int W = r >> 4;
    const int Hq = (r >> 1) & 7;
    const int f3 = r & 1;
    const int f1 = W >> 4, f2 = Hq >> 2;
    const float* xb = x + (size_t)b * 96 * 32768 + W * 1024 + Hq * 4 * 32 + f3 * 16;

    #pragma unroll
    for (int k = 0; k < 24; ++k) {
        int idx = k * 256 + threadIdx.x;
        int c = idx >> 6, i2 = idx & 63;
        xt[c][i2] = xb[(size_t)c * 32768 + (i2 >> 4) * 32 + (i2 & 15)];
    }
    __syncthreads();

    const int i = threadIdx.x & 63;
    const int g = threadIdx.x >> 6;
    const int ob = __builtin_amdgcn_readfirstlane(g * 24);
    const int B2 = (b << 5) | (g << 3) | (f1 << 2) | (f2 << 1) | f3;
    const int uoff = __builtin_amdgcn_readfirstlane(B2 * 776);
    const double* ug = uG + uoff;       // wave-uniform -> s_load

    double a[8];
    #pragma unroll
    for (int m = 0; m < 8; ++m) a[m] = ug[768 + m];
    float accN[24];
    #pragma unroll
    for (int oo = 0; oo < 24; ++oo) accN[oo] = fb[ob + oo];

    for (int c = 0; c < 96; ++c) {
        const float xv = xt[c][i];
        const double xd = (double)xv;
        const double* uc = ug + c * 8;           // 64B contiguous -> s_load_x16
        #pragma unroll
        for (int m = 0; m < 8; ++m) a[m] = fma(xd, uc[m], a[m]);
        const float* wr = wfT + c * 96 + ob;     // wave-uniform -> s_load
        #pragma unroll
        for (int oo = 0; oo < 24; ++oo) accN[oo] = fmaf(xv, wr[oo], accN[oo]);
    }

    float ss = 0.f;
    #pragma unroll
    for (int oo = 0; oo < 24; ++oo) ss = fmaf(accN[oo], accN[oo], ss);
    const float dn = fmaxf(sqrtf(ss), 1e-12f);

    const double alpha = (double)al[0];
    const double beta  = (double)be[0];
    int bm = 0; double dbest = a[0];
    if (alpha > 0.0) {
        #pragma unroll
        for (int m = 1; m < 8; ++m) if (a[m] > dbest) { dbest = a[m]; bm = m; }
    } else if (alpha < 0.0) {
        #pragma unroll
        for (int m = 1; m < 8; ++m) if (a[m] < dbest) { dbest = a[m]; bm = m; }
    }
    const double tv = beta + alpha * (dbest / (double)dn);
    const float sv = 1.f / (1.f + expf(-(float)tv));

    const int n = ((W & 15) << 8) | (((Hq & 3) * 4 + (i >> 4)) << 4) | (i & 15);
    svb[(size_t)B2 * 4096 + n] = sv;
    bmb[(size_t)B2 * 4096 + n] = (unsigned char)bm;
}

// ---------------- K_xagg: branchless mask-GEMM aggregation (no atomics) -----
__global__ __launch_bounds__(256) void k_xagg(
    const float* __restrict__ x, const float* __restrict__ svb,
    const unsigned char* __restrict__ bmb, float* __restrict__ xagg,
    float* __restrict__ cntb)
{
    __shared__ float red[256][33];
    __shared__ float red2[8][32];
    const int grp = blockIdx.x / 97;
    const int c   = blockIdx.x - grp * 97;
    const int b = grp >> 3, fff = grp & 7;
    const int f1 = fff >> 2, f2 = (fff >> 1) & 1, f3 = fff & 1;
    const int t = threadIdx.x;
    const float* xc = x + ((size_t)b * 96 + (c < 96 ? c : 0)) * 32768;
    const int sbase = f1 * 16 * 1024 + f2 * 16 * 32 + f3 * 16;

    float acc[4][8];
    #pragma unroll
    for (int g = 0; g < 4; ++g)
        #pragma unroll
        for (int m = 0; m < 8; ++m) acc[g][m] = 0.f;

    #pragma unroll 4
    for (int k = 0; k < 16; ++k) {
        const int n = k * 256 + t;
        const int s = sbase + (n >> 8) * 1024 + ((n >> 4) & 15) * 32 + (n & 15);
        const float xv = (c < 96) ? xc[s] : 1.0f;
        #pragma unroll
        for (int g = 0; g < 4; ++g) {
            const int B2g = (b << 5) | (g << 3) | fff;
            const float svv = svb[(size_t)B2g * 4096 + n];
            const int bmv = bmb[(size_t)B2g * 4096 + n];
            const float p = svv * xv;
            #pragma unroll
            for (int m = 0; m < 8; ++m)
                acc[g][m] += (bmv == m) ? p : 0.f;
        }
    }

    #pragma unroll
    for (int g = 0; g < 4; ++g)
        #pragma unroll
        for (int m = 0; m < 8; ++m) red[t][g * 8 + m] = acc[g][m];
    __syncthreads();
    {
        const int j = t & 31, part = t >> 5;
        float s = 0.f;
        #pragma unroll
        for (int kk = 0; kk < 32; ++kk) s += red[part * 32 + kk][j];
        red2[part][j] = s;
    }
    __syncthreads();
    if (t < 32) {
        float s = 0.f;
        #pragma unroll
        for (int p = 0; p < 8; ++p) s += red2[p][t];
        const int g = t >> 3, m = t & 7;
        const int B2g = (b << 5) | (g << 3) | fff;
        if (c < 96) xagg[((size_t)B2g * 8 + m) * 96 + c] = s;
        else        cntb[B2g * 8 + m] = s;
    }
}

// ---------------- K_pagg: agg = (vW.xagg + cnt*vb + vcent)/(cnt+1); pagg=P.agg
// grid 128 x 256.
__global__ __launch_bounds__(256) void k_pagg(
    const float* __restrict__ wvT, const float* __restrict__ vb,
    const float* __restrict__ wpT, const float* __restrict__ xagg,
    const float* __restrict__ cntb, const float* __restrict__ vcent,
    float* __restrict__ pagg)
{
    __shared__ float xa_l[8][96];
    __shared__ float agg_l[8][25];
    __shared__ float cnt_l[8];
    const int B2 = blockIdx.x, t = threadIdx.x;
    const int g = (B2 >> 3) & 3;
    for (int k = t; k < 768; k += 256) ((float*)xa_l)[k] = xagg[(size_t)B2 * 768 + k];
    if (t < 8) cnt_l[t] = cntb[B2 * 8 + t];
    __syncthreads();
    if (t < 192) {
        const int m = t / 24, o = t - m * 24;
        float s = 0.f;
        for (int ci = 0; ci < 96; ++ci)
            s = fmaf(wvT[ci * 96 + g * 24 + o], xa_l[m][ci], s);
        s += cnt_l[m] * vb[g * 24 + o] + vcent[(size_t)B2 * 192 + t];
        agg_l[m][o] = s / (cnt_l[m] + 1.f);
    }
    __syncthreads();
    #pragma unroll
    for (int r = 0; r < 3; ++r) {
        const int k = r * 256 + t;
        const int m = k / 96, C = k - m * 96;
        float s = 0.f;
        #pragma unroll
        for (int o = 0; o < 24; ++o)
            s = fmaf(wpT[(g * 24 + o) * 96 + C], agg_l[m][o], s);
        pagg[(size_t)B2 * 768 + k] = s;
    }
}

// ---------------- K_disp: out = pb + sum_g sv_g * pagg[B2g][bm_g] -----------
// grid 2048 = b x W x Hq x f3; block 256 = 4 co-quarters x 64 pos.
__global__ __launch_bounds__(256) void k_disp(
    const float* __restrict__ pagg, const float* __restrict__ svb,
    const unsigned char* __restrict__ bmb, const float* __restrict__ pb,
    float* __restrict__ out)
{
    __shared__ float pagg_l[4][776];   // [g][m*97+c] padded
    __shared__ float svs[4][64];
    __shared__ unsigned char bms[4][64];
    const int tile = blockIdx.x;
    const int b = tile >> 9;
    const int r = tile & 511;
    const int W = r >> 4;
    const int Hq = (r >> 1) & 7;
    const int f3 = r & 1;
    const int f1 = W >> 4, f2 = Hq >> 2;
    const int t = threadIdx.x;
    const int i = t & 63, q = t >> 6;

    const int n = ((W & 15) << 8) | ((((Hq & 3) << 2) | (i >> 4)) << 4) | (i & 15);
    {
        const int B2q = (b << 5) | (q << 3) | (f1 << 2) | (f2 << 1) | f3;
        svs[q][i] = svb[(size_t)B2q * 4096 + n];
        bms[q][i] = bmb[(size_t)B2q * 4096 + n];
    }
    for (int k = t; k < 3072; k += 256) {
        const int g = k >> 10;          // k/1024? NO: 3072 = 4*768
        const int gg = k / 768, rem = k - gg * 768;
        const int m = rem / 96, c = rem - m * 96;
        const int B2g = (b << 5) | (gg << 3) | (f1 << 2) | (f2 << 1) | f3;
        (void)g;
        pagg_l[gg][m * 97 + c] = pagg[(size_t)B2g * 768 + rem];
    }
    __syncthreads();

    const int co = q * 24;
    float acc[24];
    #pragma unroll
    for (int oo = 0; oo < 24; ++oo) acc[oo] = pb[co + oo];
    #pragma unroll
    for (int g = 0; g < 4; ++g) {
        const float sv = svs[g][i];
        const int bm = bms[g][i];
        const float* pg = &pagg_l[g][bm * 97 + co];
        #pragma unroll
        for (int oo = 0; oo < 24; ++oo) acc[oo] = fmaf(sv, pg[oo], acc[oo]);
    }
    const int s = W * 1024 + ((Hq << 2) | (i >> 4)) * 32 + f3 * 16 + (i & 15);
    #pragma unroll
    for (int oo = 0; oo < 24; ++oo)
        out[((size_t)b * 96 + co + oo) * 32768 + s] = acc[oo];
}

// ---------------- launcher --------------------------------------------------
extern "C" void kernel_launch(void* const* d_in, const int* in_sizes, int n_in,
                              void* d_out, int out_size, void* d_ws, size_t ws_size,
                              hipStream_t stream)
{
    const float* x  = (const float*)d_in[0];
    const float* fw = (const float*)d_in[1];
    const float* fb = (const float*)d_in[2];
    const float* vw = (const float*)d_in[3];
    const float* vb = (const float*)d_in[4];
    const float* pw = (const float*)d_in[5];
    const float* pb = (const float*)d_in[6];
    const float* al = (const float*)d_in[7];
    const float* be = (const float*)d_in[8];
    float* out = (float*)d_out;

    char* ws = (char*)d_ws;
    float*  wfT   = (float*)(ws);                    //   36864
    float*  wpT   = (float*)(ws + 36864);            //   36864
    float*  wvT   = (float*)(ws + 73728);            //   36864
    double* xmeanD= (double*)(ws + 110592);          //  196608
    double* chat  = (double*)(ws + 307200);          //  196608
    double* uG    = (double*)(ws + 503808);          //  794624 [128][97][8]
    float*  vcent = (float*)(ws + 1298432);          //   98304
    float*  xagg  = (float*)(ws + 1396736);          //  393216
    float*  cntb  = (float*)(ws + 1789952);          //    4096
    float*  pagg  = (float*)(ws + 1794048);          //  393216
    float*  svb   = (float*)(ws + 2187264);          // 2097152
    unsigned char* bmb = (unsigned char*)(ws + 4284416); // 524288
    // total ~4.8 MB

    k0_prep<<<36, 256, 0, stream>>>(fw, vw, pw, wfT, wvT, wpT);
    k_pool<<<96, 256, 0, stream>>>(x, xmeanD);
    k_cent<<<128, 192, 0, stream>>>(fw, fb, vw, vb, xmeanD, chat, vcent);
    k_prep_u<<<388, 256, 0, stream>>>(fw, fb, chat, uG);
    k1_conv<<<2048, 256, 0, stream>>>(x, wfT, fb, uG, al, be, svb, bmb);
    k_xagg<<<3104, 256, 0, stream>>>(x, svb, bmb, xagg, cntb);
    k_pagg<<<128, 256, 0, stream>>>(wvT, vb, wpT, xagg, cntb, vcent, pagg);
    k_disp<<<2048, 256, 0, stream>>>(pagg, svb, bmb, pb, out);
}

// Round 9
// 239.505 us; speedup vs baseline: 2.1480x; 1.0388x over previous
//
#include <hip/hip_runtime.h>
#include <hip/hip_bf16.h>

// B=4, C=96, vol 32^3; HEADS=4, HDIM=24, FOLD=2, PROP=2.
// 128 cluster batches (B2), each c=24, N=4096 points, M=8 centers.
//
// Identities:
//   argmax_m chat_m.(f/|f|) = argmax_m (u_m.x + k_m)    [u = Wf^T chat, f64]
//   sum_n sv*value_n = vW.(sum_n sv*x_n) + (sum_n sv)*vb [aggregate x]
//   out = pb + sum_g sv_g * pagg[B2g][bm_g]              [pagg = P.agg]
//
// Pipeline: kA{transpose+pool} ; kB{cent+prep_u} ; k1_conv ; k_xagg ;
//           k_pagg ; k_disp

// ---------------- K_A: weight transposes (blocks 0..35) + pool (36..419) ----
__global__ __launch_bounds__(256) void kA_prep_pool(
    const float* __restrict__ fw, const float* __restrict__ vw,
    const float* __restrict__ pw, const float* __restrict__ x,
    float* __restrict__ wfT, float* __restrict__ wvT, float* __restrict__ wpT,
    double* __restrict__ xmeanD)
{
    const int bid = blockIdx.x;
    const int t = threadIdx.x;
    if (bid < 36) {
        int k = bid * 256 + t;
        if (k < 96 * 96) {
            int o = k / 96, c = k % 96;
            wfT[c * 96 + o] = fw[o * 96 + c];
            wvT[c * 96 + o] = vw[o * 96 + c];
            wpT[c * 96 + o] = pw[o * 96 + c];
        }
        return;
    }
    // pool: block per (b,c); fully coalesced float4; f64 bins; shfl tree.
    const int bc = bid - 36;
    const int b = bc / 96, c = bc - b * 96;
    const float* xb = x + ((size_t)b * 96 + c) * 32768;

    double acc[4];   // [f1*2 + m_W] = k>>3
    #pragma unroll
    for (int a = 0; a < 4; ++a) acc[a] = 0.0;
    #pragma unroll 8
    for (int k = 0; k < 32; ++k) {
        float4 v = *(const float4*)(xb + k * 1024 + t * 4);
        double sc = (double)v.x + (double)v.y + (double)v.z + (double)v.w;
        acc[k >> 3] += sc;
    }
    // reduce across lane bits {0,3,4,5} (free bits of the octant grouping)
    #pragma unroll
    for (int a = 0; a < 4; ++a) {
        acc[a] += __shfl_xor(acc[a], 1);
        acc[a] += __shfl_xor(acc[a], 8);
        acc[a] += __shfl_xor(acc[a], 16);
        acc[a] += __shfl_xor(acc[a], 32);
    }
    if ((t & 0x39) == 0) {   // bits 0,3,4,5 clear
        const int m_D = (t >> 1) & 1, f3 = (t >> 2) & 1;
        const int m_H = (t >> 6) & 1, f2 = (t >> 7) & 1;
        #pragma unroll
        for (int a = 0; a < 4; ++a) {
            const int f1 = a >> 1, m_W = a & 1;
            const int fm = f1 * 32 + f2 * 16 + f3 * 8 + m_W * 4 + m_H * 2 + m_D;
            xmeanD[(size_t)(b * 64 + fm) * 96 + c] = acc[a] * (1.0 / 512.0);
        }
    }
}

// ---------------- K_B: centers (f64) + vcent + uG, fused per B2 -------------
// grid 128 x 256.
__global__ __launch_bounds__(256) void kB_cent_u(
    const float* __restrict__ fw, const float* __restrict__ fb,
    const float* __restrict__ vw, const float* __restrict__ vb,
    const double* __restrict__ xmeanD, double* __restrict__ uG,
    float* __restrict__ vcent)
{
    __shared__ double centL[8][24];
    __shared__ double chL[8][24];
    __shared__ double dnv[8];
    const int B2 = blockIdx.x, t = threadIdx.x;
    const int b = B2 >> 5, g = (B2 >> 3) & 3, fff = B2 & 7;
    const int ob = g * 24;
    if (t < 192) {
        const int mm = t / 24, co = t - mm * 24;
        const double* xm = xmeanD + (size_t)(b * 64 + fff * 8 + mm) * 96;
        double cF = (double)fb[ob + co];
        float  cV = vb[ob + co];
        const float* fr = fw + (ob + co) * 96;
        const float* vr = vw + (ob + co) * 96;
        for (int ci = 0; ci < 96; ++ci) {
            double xv = xm[ci];
            cF += (double)fr[ci] * xv;
            cV += vr[ci] * (float)xv;
        }
        centL[mm][co] = cF;
        vcent[(size_t)B2 * 192 + t] = cV;
    }
    __syncthreads();
    if (t < 8) {
        double ss = 0.0;
        #pragma unroll
        for (int cc = 0; cc < 24; ++cc) ss += centL[t][cc] * centL[t][cc];
        dnv[t] = fmax(sqrt(ss), 1e-12);
    }
    __syncthreads();
    if (t < 192) {
        const int mm = t / 24, co = t - mm * 24;
        chL[mm][co] = centL[mm][co] / dnv[mm];
    }
    __syncthreads();
    for (int k = t; k < 776; k += 256) {
        const int c = k >> 3, m = k & 7;
        double s = 0.0;
        if (c < 96) {
            #pragma unroll
            for (int o = 0; o < 24; ++o) s += (double)fw[(ob + o) * 96 + c] * chL[m][o];
        } else {
            #pragma unroll
            for (int o = 0; o < 24; ++o) s += (double)fb[ob + o] * chL[m][o];
        }
        uG[(size_t)B2 * 776 + k] = s;
    }
}

// ---------------- K1: fused argmax (f64 u-dots via s_load) + sv -------------
// grid 2048 = b(4) x W(32) x Hq(8) x f3(2); block 256 = 64 pos x 4 heads.
// 48-channel double-staged LDS tile (12.3 KB -> 8 blocks/CU, no tail round).
__global__ __launch_bounds__(256) void k1_conv(
    const float* __restrict__ x, const float* __restrict__ wfT,
    const float* __restrict__ fb, const double* __restrict__ uG,
    const float* __restrict__ al, const float* __restrict__ be,
    float* __restrict__ svb, unsigned char* __restrict__ bmb)
{
    __shared__ float xt[48][64];
    const int tile = blockIdx.x;
    const int b = tile >> 9;
    const int r = tile & 511;
    const int W = r >> 4;
    const int Hq = (r >> 1) & 7;
    const int f3 = r & 1;
    const int f1 = W >> 4, f2 = Hq >> 2;
    const float* xbase = x + (size_t)b * 96 * 32768 + W * 1024 + Hq * 128 + f3 * 16;
    const int t = threadIdx.x;
    const int i = t & 63;
    const int g = t >> 6;
    const int ob = __builtin_amdgcn_readfirstlane(g * 24);
    const int B2 = (b << 5) | (g << 3) | (f1 << 2) | (f2 << 1) | f3;
    const int uoff = __builtin_amdgcn_readfirstlane(B2 * 776);
    const double* ug = uG + uoff;       // wave-uniform -> s_load

    double a[8];
    #pragma unroll
    for (int m = 0; m < 8; ++m) a[m] = ug[768 + m];
    float accN[24];
    #pragma unroll
    for (int oo = 0; oo < 24; ++oo) accN[oo] = fb[ob + oo];

    #pragma unroll
    for (int half = 0; half < 2; ++half) {
        const int h0 = half * 48;
        if (half) __syncthreads();     // all reads of previous half done
        #pragma unroll
        for (int j = 0; j < 3; ++j) {
            const int q = j * 256 + t;             // 0..767
            const int row = q >> 2, e = q & 3;
            const int cl = row >> 2, hh = row & 3;
            float4 v = *(const float4*)(xbase + (size_t)(h0 + cl) * 32768 + hh * 32 + e * 4);
            *(float4*)&xt[cl][hh * 16 + e * 4] = v;
        }
        __syncthreads();
        for (int cl = 0; cl < 48; ++cl) {
            const float xv = xt[cl][i];
            const double xd = (double)xv;
            const double* uc = ug + (h0 + cl) * 8;     // 64B -> s_load_x16
            #pragma unroll
            for (int m = 0; m < 8; ++m) a[m] = fma(xd, uc[m], a[m]);
            const float* wr = wfT + (h0 + cl) * 96 + ob;  // uniform -> s_load
            #pragma unroll
            for (int oo = 0; oo < 24; ++oo) accN[oo] = fmaf(xv, wr[oo], accN[oo]);
        }
    }

    float ss = 0.f;
    #pragma unroll
    for (int oo = 0; oo < 24; ++oo) ss = fmaf(accN[oo], accN[oo], ss);
    const float dn = fmaxf(sqrtf(ss), 1e-12f);

    const double alpha = (double)al[0];
    const double beta  = (double)be[0];
    int bm = 0; double dbest = a[0];
    if (alpha > 0.0) {
        #pragma unroll
        for (int m = 1; m < 8; ++m) if (a[m] > dbest) { dbest = a[m]; bm = m; }
    } else if (alpha < 0.0) {
        #pragma unroll
        for (int m = 1; m < 8; ++m) if (a[m] < dbest) { dbest = a[m]; bm = m; }
    }
    const double tv = beta + alpha * (dbest / (double)dn);
    const float sv = 1.f / (1.f + expf(-(float)tv));

    const int n = ((W & 15) << 8) | (((Hq & 3) * 4 + (i >> 4)) << 4) | (i & 15);
    svb[(size_t)B2 * 4096 + n] = sv;
    bmb[(size_t)B2 * 4096 + n] = (unsigned char)bm;
}

// ---------------- K_xagg: branchless mask-GEMM aggregation (no atomics) -----
__global__ __launch_bounds__(256) void k_xagg(
    const float* __restrict__ x, const float* __restrict__ svb,
    const unsigned char* __restrict__ bmb, float* __restrict__ xagg,
    float* __restrict__ cntb)
{
    __shared__ float red[256][33];
    __shared__ float red2[8][32];
    const int grp = blockIdx.x / 97;
    const int c   = blockIdx.x - grp * 97;
    const int b = grp >> 3, fff = grp & 7;
    const int f1 = fff >> 2, f2 = (fff >> 1) & 1, f3 = fff & 1;
    const int t = threadIdx.x;
    const float* xc = x + ((size_t)b * 96 + (c < 96 ? c : 0)) * 32768;
    const int sbase = f1 * 16 * 1024 + f2 * 16 * 32 + f3 * 16;

    float acc[4][8];
    #pragma unroll
    for (int g = 0; g < 4; ++g)
        #pragma unroll
        for (int m = 0; m < 8; ++m) acc[g][m] = 0.f;

    #pragma unroll 4
    for (int k = 0; k < 16; ++k) {
        const int n = k * 256 + t;
        const int s = sbase + (n >> 8) * 1024 + ((n >> 4) & 15) * 32 + (n & 15);
        const float xv = (c < 96) ? xc[s] : 1.0f;
        #pragma unroll
        for (int g = 0; g < 4; ++g) {
            const int B2g = (b << 5) | (g << 3) | fff;
            const float svv = svb[(size_t)B2g * 4096 + n];
            const int bmv = bmb[(size_t)B2g * 4096 + n];
            const float p = svv * xv;
            #pragma unroll
            for (int m = 0; m < 8; ++m)
                acc[g][m] += (bmv == m) ? p : 0.f;
        }
    }

    #pragma unroll
    for (int g = 0; g < 4; ++g)
        #pragma unroll
        for (int m = 0; m < 8; ++m) red[t][g * 8 + m] = acc[g][m];
    __syncthreads();
    {
        const int j = t & 31, part = t >> 5;
        float s = 0.f;
        #pragma unroll
        for (int kk = 0; kk < 32; ++kk) s += red[part * 32 + kk][j];
        red2[part][j] = s;
    }
    __syncthreads();
    if (t < 32) {
        float s = 0.f;
        #pragma unroll
        for (int p = 0; p < 8; ++p) s += red2[p][t];
        const int g = t >> 3, m = t & 7;
        const int B2g = (b << 5) | (g << 3) | fff;
        if (c < 96) xagg[((size_t)B2g * 8 + m) * 96 + c] = s;
        else        cntb[B2g * 8 + m] = s;
    }
}

// ---------------- K_pagg: agg = (vW.xagg + cnt*vb + vcent)/(cnt+1); pagg=P.agg
__global__ __launch_bounds__(256) void k_pagg(
    const float* __restrict__ wvT, const float* __restrict__ vb,
    const float* __restrict__ wpT, const float* __restrict__ xagg,
    const float* __restrict__ cntb, const float* __restrict__ vcent,
    float* __restrict__ pagg)
{
    __shared__ float xa_l[8][96];
    __shared__ float agg_l[8][25];
    __shared__ float cnt_l[8];
    const int B2 = blockIdx.x, t = threadIdx.x;
    const int g = (B2 >> 3) & 3;
    for (int k = t; k < 768; k += 256) ((float*)xa_l)[k] = xagg[(size_t)B2 * 768 + k];
    if (t < 8) cnt_l[t] = cntb[B2 * 8 + t];
    __syncthreads();
    if (t < 192) {
        const int m = t / 24, o = t - m * 24;
        float s = 0.f;
        for (int ci = 0; ci < 96; ++ci)
            s = fmaf(wvT[ci * 96 + g * 24 + o], xa_l[m][ci], s);
        s += cnt_l[m] * vb[g * 24 + o] + vcent[(size_t)B2 * 192 + t];
        agg_l[m][o] = s / (cnt_l[m] + 1.f);
    }
    __syncthreads();
    #pragma unroll
    for (int r = 0; r < 3; ++r) {
        const int k = r * 256 + t;
        const int m = k / 96, C = k - m * 96;
        float s = 0.f;
        #pragma unroll
        for (int o = 0; o < 24; ++o)
            s = fmaf(wpT[(g * 24 + o) * 96 + C], agg_l[m][o], s);
        pagg[(size_t)B2 * 768 + k] = s;
    }
}

// ---------------- K_disp: out = pb + sum_g sv_g * pagg[B2g][bm_g] -----------
__global__ __launch_bounds__(256) void k_disp(
    const float* __restrict__ pagg, const float* __restrict__ svb,
    const unsigned char* __restrict__ bmb, const float* __restrict__ pb,
    float* __restrict__ out)
{
    __shared__ float pagg_l[4][776];   // [g][m*97+c] padded
    __shared__ float svs[4][64];
    __shared__ unsigned char bms[4][64];
    const int tile = blockIdx.x;
    const int b = tile >> 9;
    const int r = tile & 511;
    const int W = r >> 4;
    const int Hq = (r >> 1) & 7;
    const int f3 = r & 1;
    const int f1 = W >> 4, f2 = Hq >> 2;
    const int t = threadIdx.x;
    const int i = t & 63, q = t >> 6;

    const int n = ((W & 15) << 8) | ((((Hq & 3) << 2) | (i >> 4)) << 4) | (i & 15);
    {
        const int B2q = (b << 5) | (q << 3) | (f1 << 2) | (f2 << 1) | f3;
        svs[q][i] = svb[(size_t)B2q * 4096 + n];
        bms[q][i] = bmb[(size_t)B2q * 4096 + n];
    }
    for (int k = t; k < 3072; k += 256) {
        const int gg = k / 768, rem = k - gg * 768;
        const int m = rem / 96, c = rem - m * 96;
        const int B2g = (b << 5) | (gg << 3) | (f1 << 2) | (f2 << 1) | f3;
        pagg_l[gg][m * 97 + c] = pagg[(size_t)B2g * 768 + rem];
    }
    __syncthreads();

    const int co = q * 24;
    float acc[24];
    #pragma unroll
    for (int oo = 0; oo < 24; ++oo) acc[oo] = pb[co + oo];
    #pragma unroll
    for (int g = 0; g < 4; ++g) {
        const float sv = svs[g][i];
        const int bm = bms[g][i];
        const float* pg = &pagg_l[g][bm * 97 + co];
        #pragma unroll
        for (int oo = 0; oo < 24; ++oo) acc[oo] = fmaf(sv, pg[oo], acc[oo]);
    }
    const int s = W * 1024 + ((Hq << 2) | (i >> 4)) * 32 + f3 * 16 + (i & 15);
    #pragma unroll
    for (int oo = 0; oo < 24; ++oo)
        out[((size_t)b * 96 + co + oo) * 32768 + s] = acc[oo];
}

// ---------------- launcher --------------------------------------------------
extern "C" void kernel_launch(void* const* d_in, const int* in_sizes, int n_in,
                              void* d_out, int out_size, void* d_ws, size_t ws_size,
                              hipStream_t stream)
{
    const float* x  = (const float*)d_in[0];
    const float* fw = (const float*)d_in[1];
    const float* fb = (const float*)d_in[2];
    const float* vw = (const float*)d_in[3];
    const float* vb = (const float*)d_in[4];
    const float* pw = (const float*)d_in[5];
    const float* pb = (const float*)d_in[6];
    const float* al = (const float*)d_in[7];
    const float* be = (const float*)d_in[8];
    float* out = (float*)d_out;

    char* ws = (char*)d_ws;
    float*  wfT   = (float*)(ws);                    //   36864
    float*  wvT   = (float*)(ws + 36864);            //   36864
    float*  wpT   = (float*)(ws + 73728);            //   36864
    double* xmeanD= (double*)(ws + 110592);          //  196608
    double* uG    = (double*)(ws + 307200);          //  794624 [128][97][8]
    float*  vcent = (float*)(ws + 1101824);          //   98304
    float*  xagg  = (float*)(ws + 1200128);          //  393216
    float*  cntb  = (float*)(ws + 1593344);          //    4096
    float*  pagg  = (float*)(ws + 1597440);          //  393216
    float*  svb   = (float*)(ws + 1990656);          // 2097152
    unsigned char* bmb = (unsigned char*)(ws + 4087808); // 524288
    // total ~4.6 MB

    kA_prep_pool<<<420, 256, 0, stream>>>(fw, vw, pw, x, wfT, wvT, wpT, xmeanD);
    kB_cent_u<<<128, 256, 0, stream>>>(fw, fb, vw, vb, xmeanD, uG, vcent);
    k1_conv<<<2048, 256, 0, stream>>>(x, wfT, fb, uG, al, be, svb, bmb);
    k_xagg<<<3104, 256, 0, stream>>>(x, svb, bmb, xagg, cntb);
    k_pagg<<<128, 256, 0, stream>>>(wvT, vb, wpT, xagg, cntb, vcent, pagg);
    k_disp<<<2048, 256, 0, stream>>>(pagg, svb, bmb, pb, out);
}